// Round 1
// baseline (962.803 us; speedup 1.0000x reference)
//
#include <hip/hip_runtime.h>
#include <math.h>

#define E_TOT   320000
#define NN_TOT  10000
#define D_NODE  128
#define D_EDGE  32
#define D_IN    288
#define D_HID   192
#define D_OUT   128
#define EB      32      // edges per block

// ---------------------------------------------------------------------------
// Edge MLP: msg[e] = (tanh(concat(n[s],n[r],ef) @ W1 + b1)) @ W2 + b2
// 256 threads = 4 waves; each wave owns 8 edges; lane l owns hidden columns
// {l, l+64, l+128} then output columns {l, l+64}.
// LDS reads in the FMA loops are wave-uniform (broadcast, conflict-free).
// ---------------------------------------------------------------------------
__global__ __launch_bounds__(256) void edge_mlp_kernel(
    const float* __restrict__ n_embed, const float* __restrict__ e_embed,
    const int* __restrict__ senders, const int* __restrict__ receivers,
    const float* __restrict__ W1, const float* __restrict__ b1,
    const float* __restrict__ W2, const float* __restrict__ b2,
    float* __restrict__ msg_out, int atomic_mode)
{
    __shared__ float s_inp[EB][D_IN];   // 36864 B
    __shared__ float s_h[EB][D_HID];    // 24576 B
    const int tid = threadIdx.x;
    const int e0  = blockIdx.x * EB;

    // ---- stage gathered input tile: 32 edges x 72 float4 ----
    for (int idx = tid; idx < EB * (D_IN / 4); idx += 256) {
        int e = idx / (D_IN / 4);
        int p = idx - e * (D_IN / 4);
        int ge = e0 + e;
        float4 v;
        if (p < D_NODE / 4) {
            v = ((const float4*)(n_embed + (size_t)senders[ge] * D_NODE))[p];
        } else if (p < D_NODE / 2) {
            v = ((const float4*)(n_embed + (size_t)receivers[ge] * D_NODE))[p - D_NODE / 4];
        } else {
            v = ((const float4*)(e_embed + (size_t)ge * D_EDGE))[p - D_NODE / 2];
        }
        *(float4*)&s_inp[e][p * 4] = v;
    }
    __syncthreads();

    const int wave  = tid >> 6;
    const int lane  = tid & 63;
    const int ebase = wave * 8;

    // ---- layer 1: h = tanh(inp @ W1 + b1) ----
    float acc0[8], acc1[8], acc2[8];
    #pragma unroll
    for (int e = 0; e < 8; ++e) acc0[e] = acc1[e] = acc2[e] = 0.f;

    for (int i = 0; i < D_IN; ++i) {
        float w0 = W1[i * D_HID + lane];
        float w1 = W1[i * D_HID + lane + 64];
        float w2 = W1[i * D_HID + lane + 128];
        #pragma unroll
        for (int e = 0; e < 8; ++e) {
            float x = s_inp[ebase + e][i];
            acc0[e] = fmaf(x, w0, acc0[e]);
            acc1[e] = fmaf(x, w1, acc1[e]);
            acc2[e] = fmaf(x, w2, acc2[e]);
        }
    }
    {
        float bj0 = b1[lane], bj1 = b1[lane + 64], bj2 = b1[lane + 128];
        #pragma unroll
        for (int e = 0; e < 8; ++e) {
            s_h[ebase + e][lane]       = tanhf(acc0[e] + bj0);
            s_h[ebase + e][lane + 64]  = tanhf(acc1[e] + bj1);
            s_h[ebase + e][lane + 128] = tanhf(acc2[e] + bj2);
        }
    }
    __syncthreads();

    // ---- layer 2: msg = h @ W2 + b2 ----
    float m0[8], m1[8];
    #pragma unroll
    for (int e = 0; e < 8; ++e) m0[e] = m1[e] = 0.f;

    for (int j = 0; j < D_HID; ++j) {
        float w0 = W2[j * D_OUT + lane];
        float w1 = W2[j * D_OUT + lane + 64];
        #pragma unroll
        for (int e = 0; e < 8; ++e) {
            float hh = s_h[ebase + e][j];
            m0[e] = fmaf(hh, w0, m0[e]);
            m1[e] = fmaf(hh, w1, m1[e]);
        }
    }
    const float bd0 = b2[lane], bd1 = b2[lane + 64];
    if (!atomic_mode) {
        #pragma unroll
        for (int e = 0; e < 8; ++e) {
            size_t ge = (size_t)(e0 + ebase + e);
            msg_out[ge * D_OUT + lane]      = m0[e] + bd0;
            msg_out[ge * D_OUT + lane + 64] = m1[e] + bd1;
        }
    } else {
        #pragma unroll
        for (int e = 0; e < 8; ++e) {
            int ge = e0 + ebase + e;
            int sn = senders[ge];
            atomicAdd(&msg_out[(size_t)sn * D_OUT + lane],      m0[e] + bd0);
            atomicAdd(&msg_out[(size_t)sn * D_OUT + lane + 64], m1[e] + bd1);
        }
    }
}

__device__ inline int lower_bound_dev(const int* __restrict__ a, int n, int key)
{
    int lo = 0, hi = n;
    while (lo < hi) {
        int mid = (lo + hi) >> 1;
        if (a[mid] < key) lo = mid + 1; else hi = mid;
    }
    return lo;
}

// one block per node; senders sorted so the segment is contiguous
__global__ __launch_bounds__(128) void seg_mean_kernel(
    const float* __restrict__ msg, const int* __restrict__ senders,
    float* __restrict__ out)
{
    int n = blockIdx.x;
    int d = threadIdx.x;
    int s0 = lower_bound_dev(senders, E_TOT, n);
    int s1 = lower_bound_dev(senders, E_TOT, n + 1);
    float sum = 0.f;
    for (int e = s0; e < s1; ++e) sum += msg[(size_t)e * D_OUT + d];
    int cnt = s1 - s0;
    out[(size_t)n * D_OUT + d] = (cnt > 0) ? sum / (float)cnt : 0.f;
}

__global__ void zero_kernel(float* p, int n)
{
    int i = blockIdx.x * blockDim.x + threadIdx.x;
    if (i < n) p[i] = 0.f;
}

__global__ __launch_bounds__(128) void div_count_kernel(
    const int* __restrict__ senders, float* __restrict__ out)
{
    int n = blockIdx.x;
    int d = threadIdx.x;
    int s0 = lower_bound_dev(senders, E_TOT, n);
    int s1 = lower_bound_dev(senders, E_TOT, n + 1);
    int cnt = s1 - s0;
    if (cnt > 0) out[(size_t)n * D_OUT + d] /= (float)cnt;
}

extern "C" void kernel_launch(void* const* d_in, const int* in_sizes, int n_in,
                              void* d_out, int out_size, void* d_ws, size_t ws_size,
                              hipStream_t stream)
{
    const float* n_embed  = (const float*)d_in[0];
    const float* e_embed  = (const float*)d_in[1];
    const int*   senders  = (const int*)d_in[2];
    const int*   receivers= (const int*)d_in[3];
    const float* W1       = (const float*)d_in[4];
    const float* b1       = (const float*)d_in[5];
    const float* W2       = (const float*)d_in[6];
    const float* b2       = (const float*)d_in[7];
    float* out = (float*)d_out;

    const size_t msg_bytes = (size_t)E_TOT * D_OUT * sizeof(float);
    if (ws_size >= msg_bytes) {
        // deterministic two-pass: msg scratch in workspace, then segment mean
        float* msg = (float*)d_ws;
        edge_mlp_kernel<<<E_TOT / EB, 256, 0, stream>>>(
            n_embed, e_embed, senders, receivers, W1, b1, W2, b2, msg, 0);
        seg_mean_kernel<<<NN_TOT, 128, 0, stream>>>(msg, senders, out);
    } else {
        // fallback: atomic accumulate into out, then divide by counts
        int n = NN_TOT * D_OUT;
        zero_kernel<<<(n + 255) / 256, 256, 0, stream>>>(out, n);
        edge_mlp_kernel<<<E_TOT / EB, 256, 0, stream>>>(
            n_embed, e_embed, senders, receivers, W1, b1, W2, b2, out, 1);
        div_count_kernel<<<NN_TOT, 128, 0, stream>>>(senders, out);
    }
}

// Round 2
// 121.078 us; speedup vs baseline: 7.9519x; 7.9519x over previous
//
#include <hip/hip_runtime.h>

#define E_TOT 320000
#define NN    10000
#define DN    128
#define DE    32
#define DI    288    // 2*DN + DE
#define DH    192
#define DO    128
#define EB    64     // edges per block

typedef __attribute__((ext_vector_type(8))) short bf16x8;
typedef __attribute__((ext_vector_type(4))) float f32x4;

// fragment-major packed weights (bf16), rewritten every launch
#define W1_FRAGS (9*12*64)   // kk(9) x ntile(12) x lane(64), 8 bf16 each
#define W2_FRAGS (6*8*64)    // kk(6) x ntile(8)  x lane(64)
__device__ __align__(16) unsigned short g_p1[W1_FRAGS * 8];
__device__ __align__(16) unsigned short g_p2[W2_FRAGS * 8];

__device__ __forceinline__ unsigned short f2bf(float f) {
    union { float f; unsigned u; } v; v.f = f;
    return (unsigned short)((v.u + 0x7FFFu + ((v.u >> 16) & 1u)) >> 16);
}

// ---------------------------------------------------------------------------
// Pack W1 [288][192] and W2 [192][128] (fp32, row-major) into per-lane MFMA
// B-fragments: frag(kk,nt,lane)[i] = W[kk*32 + (lane>>4)*8 + i][nt*16 + (lane&15)]
// ---------------------------------------------------------------------------
__global__ void pack_weights(const float* __restrict__ W1, const float* __restrict__ W2)
{
    int f = blockIdx.x * 256 + threadIdx.x;
    unsigned short tmp[8];
    if (f < W1_FRAGS) {
        int kk = f / (12 * 64);
        int nt = (f >> 6) % 12;
        int lane = f & 63;
        int r0 = kk * 32 + ((lane >> 4) << 3);
        int c  = nt * 16 + (lane & 15);
        #pragma unroll
        for (int i = 0; i < 8; ++i) tmp[i] = f2bf(W1[(r0 + i) * DH + c]);
        *(uint4*)(g_p1 + (size_t)f * 8) = *(const uint4*)tmp;
    } else if (f < W1_FRAGS + W2_FRAGS) {
        int f2 = f - W1_FRAGS;
        int kk = f2 / (8 * 64);
        int nt = (f2 >> 6) % 8;
        int lane = f2 & 63;
        int r0 = kk * 32 + ((lane >> 4) << 3);
        int c  = nt * 16 + (lane & 15);
        #pragma unroll
        for (int i = 0; i < 8; ++i) tmp[i] = f2bf(W2[(r0 + i) * DO + c]);
        *(uint4*)(g_p2 + (size_t)f2 * 8) = *(const uint4*)tmp;
    }
}

__global__ void zero_out(float* __restrict__ p)
{
    int i = blockIdx.x * 256 + threadIdx.x;
    if (i < NN * DO) p[i] = 0.f;
}

// ---------------------------------------------------------------------------
// Fused: gather -> bf16 -> GEMM1 (MFMA) -> tanh -> GEMM2 (MFMA) -> in-block
// segment reduce (senders sorted) -> atomicAdd into out.
// 256 threads = 4 waves; waves split the N dimension (weights loaded once).
// LDS tiles alias one buffer, separated by barriers:
//   s_inp[64][296] bf16 (37888B) -> s_h[64][200] bf16 (25600B) -> s_msg[64][132] f32 (33792B)
// ---------------------------------------------------------------------------
__global__ __launch_bounds__(256) void edge_mlp_mfma(
    const float* __restrict__ n_embed, const float* __restrict__ e_embed,
    const int* __restrict__ senders, const int* __restrict__ receivers,
    const float* __restrict__ b1, const float* __restrict__ b2,
    float* __restrict__ out)
{
    __shared__ __align__(16) char s_buf[EB * 296 * 2];
    __shared__ int s_send[EB];
    unsigned short (*s_inp)[296] = (unsigned short(*)[296])s_buf;
    unsigned short (*s_h)[200]   = (unsigned short(*)[200])s_buf;
    float          (*s_msg)[132] = (float(*)[132])s_buf;

    const int tid  = threadIdx.x;
    const int e0   = blockIdx.x * EB;
    const int lane = tid & 63;
    const int w    = tid >> 6;
    const int arow = lane & 15;          // M-row / N-col within a 16-tile
    const int akb  = (lane >> 4) * 8;    // K-subblock base
    const int rbase = (lane >> 4) * 4;   // C/D row base

    if (tid < EB) s_send[tid] = senders[e0 + tid];

    // ---- phase 1: stage gathered input tile as bf16 (4 threads per edge) ----
    {
        const int e = tid >> 2, c = tid & 3;
        const float* srow = n_embed + (size_t)senders[e0 + e] * DN;
        const float* rrow = n_embed + (size_t)receivers[e0 + e] * DN;
        const float* erow = e_embed + (size_t)(e0 + e) * DE;
        #pragma unroll
        for (int it = 0; it < 18; ++it) {
            int p = c + 4 * it;   // float4 position 0..71
            float4 v;
            if (it < 8)       v = ((const float4*)srow)[p];
            else if (it < 16) v = ((const float4*)rrow)[p - 32];
            else              v = ((const float4*)erow)[p - 64];
            unsigned short t[4] = { f2bf(v.x), f2bf(v.y), f2bf(v.z), f2bf(v.w) };
            *(uint2*)&s_inp[e][p * 4] = *(const uint2*)t;
        }
    }
    __syncthreads();

    // ---- phase 2: GEMM1  h_acc[64][48 per wave] = inp @ W1 ----
    f32x4 acc1[4][3];
    #pragma unroll
    for (int mt = 0; mt < 4; ++mt)
        #pragma unroll
        for (int j = 0; j < 3; ++j) acc1[mt][j] = (f32x4){0.f, 0.f, 0.f, 0.f};

    for (int kk = 0; kk < 9; ++kk) {
        bf16x8 a[4], b[3];
        #pragma unroll
        for (int mt = 0; mt < 4; ++mt)
            a[mt] = *(const bf16x8*)&s_inp[mt * 16 + arow][kk * 32 + akb];
        #pragma unroll
        for (int j = 0; j < 3; ++j)
            b[j] = *(const bf16x8*)(g_p1 + (((size_t)kk * 12 + (3 * w + j)) * 64 + lane) * 8);
        #pragma unroll
        for (int mt = 0; mt < 4; ++mt)
            #pragma unroll
            for (int j = 0; j < 3; ++j)
                acc1[mt][j] = __builtin_amdgcn_mfma_f32_16x16x32_bf16(a[mt], b[j], acc1[mt][j], 0, 0, 0);
    }
    __syncthreads();   // everyone done reading s_inp

    // ---- phase 3: bias + tanh -> s_h (bf16) ----
    {
        float bj[3];
        #pragma unroll
        for (int j = 0; j < 3; ++j) bj[j] = b1[48 * w + 16 * j + arow];
        #pragma unroll
        for (int mt = 0; mt < 4; ++mt)
            #pragma unroll
            for (int j = 0; j < 3; ++j)
                #pragma unroll
                for (int r = 0; r < 4; ++r) {
                    float x = acc1[mt][j][r] + bj[j];
                    // tanh(x) = 1 - 2/(e^{2x}+1); __expf -> v_exp_f32
                    float t = __expf(x + x);
                    float th = 1.0f - 2.0f * __builtin_amdgcn_rcpf(t + 1.0f);
                    s_h[mt * 16 + rbase + r][48 * w + 16 * j + arow] = f2bf(th);
                }
    }
    __syncthreads();

    // ---- phase 4: GEMM2  msg[64][32 per wave] = h @ W2 ----
    f32x4 acc2[4][2];
    #pragma unroll
    for (int mt = 0; mt < 4; ++mt)
        #pragma unroll
        for (int j = 0; j < 2; ++j) acc2[mt][j] = (f32x4){0.f, 0.f, 0.f, 0.f};

    for (int kk = 0; kk < 6; ++kk) {
        bf16x8 a[4], b[2];
        #pragma unroll
        for (int mt = 0; mt < 4; ++mt)
            a[mt] = *(const bf16x8*)&s_h[mt * 16 + arow][kk * 32 + akb];
        #pragma unroll
        for (int j = 0; j < 2; ++j)
            b[j] = *(const bf16x8*)(g_p2 + (((size_t)kk * 8 + (2 * w + j)) * 64 + lane) * 8);
        #pragma unroll
        for (int mt = 0; mt < 4; ++mt)
            #pragma unroll
            for (int j = 0; j < 2; ++j)
                acc2[mt][j] = __builtin_amdgcn_mfma_f32_16x16x32_bf16(a[mt], b[j], acc2[mt][j], 0, 0, 0);
    }
    __syncthreads();   // everyone done reading s_h

    // ---- phase 5: msg (+bias) -> s_msg (fp32) ----
    {
        float bd[2];
        #pragma unroll
        for (int j = 0; j < 2; ++j) bd[j] = b2[32 * w + 16 * j + arow];
        #pragma unroll
        for (int mt = 0; mt < 4; ++mt)
            #pragma unroll
            for (int j = 0; j < 2; ++j)
                #pragma unroll
                for (int r = 0; r < 4; ++r)
                    s_msg[mt * 16 + rbase + r][32 * w + 16 * j + arow] = acc2[mt][j][r] + bd[j];
    }
    __syncthreads();

    // ---- phase 6: in-block segment reduce over sorted senders, atomic flush ----
    {
        const int c  = tid & 127;
        const int r0 = (tid >> 7) * 32;
        float sum = 0.f;
        int cur = s_send[r0];
        for (int e = r0; e < r0 + 32; ++e) {
            sum += s_msg[e][c];
            int nxt = (e + 1 < r0 + 32) ? s_send[e + 1] : -1;
            if (nxt != cur) {
                atomicAdd(&out[(size_t)cur * DO + c], sum);
                sum = 0.f;
                cur = nxt;
            }
        }
    }
}

// divide each node row by its edge count (senders sorted -> binary search)
__global__ __launch_bounds__(128) void div_count(
    const int* __restrict__ senders, float* __restrict__ out)
{
    int n = blockIdx.x, d = threadIdx.x;
    int lo = 0, hi = E_TOT;
    while (lo < hi) { int m = (lo + hi) >> 1; if (senders[m] < n) lo = m + 1; else hi = m; }
    int s0 = lo;
    hi = E_TOT;
    while (lo < hi) { int m = (lo + hi) >> 1; if (senders[m] < n + 1) lo = m + 1; else hi = m; }
    int cnt = lo - s0;
    if (cnt > 1) out[(size_t)n * DO + d] *= (1.0f / (float)cnt);
}

extern "C" void kernel_launch(void* const* d_in, const int* in_sizes, int n_in,
                              void* d_out, int out_size, void* d_ws, size_t ws_size,
                              hipStream_t stream)
{
    const float* n_embed   = (const float*)d_in[0];
    const float* e_embed   = (const float*)d_in[1];
    const int*   senders   = (const int*)d_in[2];
    const int*   receivers = (const int*)d_in[3];
    const float* W1        = (const float*)d_in[4];
    const float* b1        = (const float*)d_in[5];
    const float* W2        = (const float*)d_in[6];
    const float* b2        = (const float*)d_in[7];
    float* out = (float*)d_out;

    pack_weights<<<(W1_FRAGS + W2_FRAGS + 255) / 256, 256, 0, stream>>>(W1, W2);
    zero_out<<<(NN * DO + 255) / 256, 256, 0, stream>>>(out);
    edge_mlp_mfma<<<E_TOT / EB, 256, 0, stream>>>(
        n_embed, e_embed, senders, receivers, b1, b2, out);
    div_count<<<NN, 128, 0, stream>>>(senders, out);
}

// Round 3
// 107.738 us; speedup vs baseline: 8.9365x; 1.1238x over previous
//
#include <hip/hip_runtime.h>

#define E_TOT 320000
#define NN    10000
#define DN    128
#define DE    32
#define DH    192
#define DO    128
#define EB    64

typedef __attribute__((ext_vector_type(8))) short bf16x8;
typedef __attribute__((ext_vector_type(4))) float f32x4;

// fragment-major packed weights (bf16), rewritten every launch
#define W1_FRAGS (9*12*64)   // kk(9: 0-3 sender,4-7 recv,8 edge) x ntile(12) x lane(64)
#define W2_FRAGS (6*8*64)    // kk(6) x ntile(8) x lane(64)
__device__ __align__(16) unsigned short g_p1[W1_FRAGS * 8];
__device__ __align__(16) unsigned short g_p2[W2_FRAGS * 8];

__device__ __forceinline__ unsigned short f2bf(float f) {
    union { float f; unsigned u; } v; v.f = f;
    return (unsigned short)((v.u + 0x7FFFu + ((v.u >> 16) & 1u)) >> 16);
}

__global__ void pack_weights(const float* __restrict__ W1, const float* __restrict__ W2)
{
    int f = blockIdx.x * 256 + threadIdx.x;
    unsigned short tmp[8];
    if (f < W1_FRAGS) {
        int kk = f / (12 * 64);
        int nt = (f >> 6) % 12;
        int lane = f & 63;
        int r0 = kk * 32 + ((lane >> 4) << 3);
        int c  = nt * 16 + (lane & 15);
        #pragma unroll
        for (int i = 0; i < 8; ++i) tmp[i] = f2bf(W1[(r0 + i) * DH + c]);
        *(uint4*)(g_p1 + (size_t)f * 8) = *(const uint4*)tmp;
    } else if (f < W1_FRAGS + W2_FRAGS) {
        int f2 = f - W1_FRAGS;
        int kk = f2 / (8 * 64);
        int nt = (f2 >> 6) % 8;
        int lane = f2 & 63;
        int r0 = kk * 32 + ((lane >> 4) << 3);
        int c  = nt * 16 + (lane & 15);
        #pragma unroll
        for (int i = 0; i < 8; ++i) tmp[i] = f2bf(W2[(r0 + i) * DO + c]);
        *(uint4*)(g_p2 + (size_t)f2 * 8) = *(const uint4*)tmp;
    }
}

__global__ void zero_out(float* __restrict__ p)
{
    int i = blockIdx.x * 256 + threadIdx.x;
    if (i < NN * DO) p[i] = 0.f;
}

// ---------------------------------------------------------------------------
// Node projections: P_s = n_embed @ W1[0:128] + b1   (blockIdx.y == 0)
//                   P_r = n_embed @ W1[128:256]      (blockIdx.y == 1)
// Only 10000 rows each instead of 320000 -> 35x less GEMM1 node work.
// ---------------------------------------------------------------------------
__global__ __launch_bounds__(256) void node_proj(
    const float* __restrict__ n_embed, const float* __restrict__ b1,
    float* __restrict__ P)
{
    __shared__ __align__(16) unsigned short s_a[64][136];
    const int tid  = threadIdx.x;
    const int half = blockIdx.y;
    const int n0   = blockIdx.x * 64;

    #pragma unroll
    for (int it = 0; it < 8; ++it) {
        int idx = tid + it * 256;           // 64 rows x 32 float4
        int row = idx >> 5;
        int c   = idx & 31;
        float4 v = make_float4(0.f, 0.f, 0.f, 0.f);
        if (n0 + row < NN) v = ((const float4*)(n_embed + (size_t)(n0 + row) * DN))[c];
        unsigned short t[4] = { f2bf(v.x), f2bf(v.y), f2bf(v.z), f2bf(v.w) };
        *(uint2*)&s_a[row][c * 4] = *(const uint2*)t;
    }
    __syncthreads();

    const int lane = tid & 63, w = tid >> 6;
    const int arow = lane & 15, akb = (lane >> 4) * 8, rbase = (lane >> 4) * 4;

    f32x4 acc[4][3];
    #pragma unroll
    for (int mt = 0; mt < 4; ++mt)
        #pragma unroll
        for (int j = 0; j < 3; ++j) acc[mt][j] = (f32x4){0.f, 0.f, 0.f, 0.f};

    for (int kk = 0; kk < 4; ++kk) {
        bf16x8 a[4], b[3];
        #pragma unroll
        for (int mt = 0; mt < 4; ++mt)
            a[mt] = *(const bf16x8*)&s_a[mt * 16 + arow][kk * 32 + akb];
        #pragma unroll
        for (int j = 0; j < 3; ++j)
            b[j] = *(const bf16x8*)(g_p1 + (((size_t)(kk + 4 * half) * 12 + (3 * w + j)) * 64 + lane) * 8);
        #pragma unroll
        for (int mt = 0; mt < 4; ++mt)
            #pragma unroll
            for (int j = 0; j < 3; ++j)
                acc[mt][j] = __builtin_amdgcn_mfma_f32_16x16x32_bf16(a[mt], b[j], acc[mt][j], 0, 0, 0);
    }

    float* Pout = P + (size_t)half * NN * DH;
    float bj[3];
    #pragma unroll
    for (int j = 0; j < 3; ++j) bj[j] = (half == 0) ? b1[48 * w + 16 * j + arow] : 0.f;
    #pragma unroll
    for (int mt = 0; mt < 4; ++mt)
        #pragma unroll
        for (int j = 0; j < 3; ++j)
            #pragma unroll
            for (int r = 0; r < 4; ++r) {
                int row = n0 + mt * 16 + rbase + r;
                if (row < NN)
                    Pout[(size_t)row * DH + 48 * w + 16 * j + arow] = acc[mt][j][r] + bj[j];
            }
}

// ---------------------------------------------------------------------------
// Fused edge kernel: K=32 edge GEMM (MFMA) + gathered P_s/P_r accumulator add
// + tanh -> GEMM2 -> in-block segment reduce -> atomics.
// ---------------------------------------------------------------------------
__global__ __launch_bounds__(256, 4) void edge_mlp2(
    const float* __restrict__ e_embed,
    const int* __restrict__ senders, const int* __restrict__ receivers,
    const float* __restrict__ Ps, const float* __restrict__ Pr,
    const float* __restrict__ b2, float* __restrict__ out)
{
    __shared__ __align__(16) char s_buf[EB * 132 * 4];      // 33792 B
    __shared__ __align__(16) unsigned short s_e[EB][40];    // 5120 B
    __shared__ int s_send[EB];
    unsigned short (*s_h)[200] = (unsigned short(*)[200])s_buf;  // alias
    float          (*s_msg)[132] = (float(*)[132])s_buf;         // alias

    const int tid  = threadIdx.x;
    const int e0   = blockIdx.x * EB;
    const int lane = tid & 63;
    const int w    = tid >> 6;
    const int arow = lane & 15;
    const int akb  = (lane >> 4) * 8;
    const int rbase = (lane >> 4) * 4;
    const int cw   = 48 * w + arow;   // this lane's base hidden column

    // ---- phase 1: stage e_embed tile (contiguous!) + senders ----
    if (tid < EB) s_send[tid] = senders[e0 + tid];
    #pragma unroll
    for (int it = 0; it < 2; ++it) {
        int idx = tid + it * 256;       // 64 rows x 8 float4
        int row = idx >> 3;
        int c   = idx & 7;
        float4 v = ((const float4*)(e_embed + (size_t)(e0 + row) * DE))[c];
        unsigned short t[4] = { f2bf(v.x), f2bf(v.y), f2bf(v.z), f2bf(v.w) };
        *(uint2*)&s_e[row][c * 4] = *(const uint2*)t;
    }
    __syncthreads();

    // ---- phase 2: GEMM1e  acc1 = e_embed_tile @ W1_edge  (K=32, 1 step) ----
    f32x4 acc1[4][3];
    {
        bf16x8 a[4], b[3];
        #pragma unroll
        for (int mt = 0; mt < 4; ++mt)
            a[mt] = *(const bf16x8*)&s_e[mt * 16 + arow][akb];
        #pragma unroll
        for (int j = 0; j < 3; ++j)
            b[j] = *(const bf16x8*)(g_p1 + (((size_t)8 * 12 + (3 * w + j)) * 64 + lane) * 8);
        #pragma unroll
        for (int mt = 0; mt < 4; ++mt)
            #pragma unroll
            for (int j = 0; j < 3; ++j) {
                f32x4 z = (f32x4){0.f, 0.f, 0.f, 0.f};
                acc1[mt][j] = __builtin_amdgcn_mfma_f32_16x16x32_bf16(a[mt], b[j], z, 0, 0, 0);
            }
    }

    // ---- phase 3: gather P_s[s]+P_r[r], add, tanh -> s_h (bf16) ----
    #pragma unroll
    for (int mt = 0; mt < 4; ++mt) {
        int sidx[4], ridx[4];
        #pragma unroll
        for (int r = 0; r < 4; ++r) {
            int e = e0 + mt * 16 + rbase + r;
            sidx[r] = senders[e];
            ridx[r] = receivers[e];
        }
        float psv[3][4], prv[3][4];
        #pragma unroll
        for (int j = 0; j < 3; ++j)
            #pragma unroll
            for (int r = 0; r < 4; ++r) {
                psv[j][r] = Ps[(size_t)sidx[r] * DH + cw + 16 * j];
                prv[j][r] = Pr[(size_t)ridx[r] * DH + cw + 16 * j];
            }
        #pragma unroll
        for (int j = 0; j < 3; ++j)
            #pragma unroll
            for (int r = 0; r < 4; ++r) {
                float x = acc1[mt][j][r] + psv[j][r] + prv[j][r];
                float t = __expf(x + x);
                float th = 1.0f - 2.0f * __builtin_amdgcn_rcpf(t + 1.0f);
                s_h[mt * 16 + rbase + r][cw + 16 * j] = f2bf(th);
            }
    }
    __syncthreads();

    // ---- phase 4: GEMM2  msg = h @ W2 ----
    f32x4 acc2[4][2];
    #pragma unroll
    for (int mt = 0; mt < 4; ++mt)
        #pragma unroll
        for (int j = 0; j < 2; ++j) acc2[mt][j] = (f32x4){0.f, 0.f, 0.f, 0.f};

    for (int kk = 0; kk < 6; ++kk) {
        bf16x8 a[4], b[2];
        #pragma unroll
        for (int mt = 0; mt < 4; ++mt)
            a[mt] = *(const bf16x8*)&s_h[mt * 16 + arow][kk * 32 + akb];
        #pragma unroll
        for (int j = 0; j < 2; ++j)
            b[j] = *(const bf16x8*)(g_p2 + (((size_t)kk * 8 + (2 * w + j)) * 64 + lane) * 8);
        #pragma unroll
        for (int mt = 0; mt < 4; ++mt)
            #pragma unroll
            for (int j = 0; j < 2; ++j)
                acc2[mt][j] = __builtin_amdgcn_mfma_f32_16x16x32_bf16(a[mt], b[j], acc2[mt][j], 0, 0, 0);
    }
    __syncthreads();   // s_h reads done (s_msg aliases it)

    // ---- phase 5: msg (+bias) -> s_msg (fp32) ----
    {
        float bd[2];
        #pragma unroll
        for (int j = 0; j < 2; ++j) bd[j] = b2[32 * w + 16 * j + arow];
        #pragma unroll
        for (int mt = 0; mt < 4; ++mt)
            #pragma unroll
            for (int j = 0; j < 2; ++j)
                #pragma unroll
                for (int r = 0; r < 4; ++r)
                    s_msg[mt * 16 + rbase + r][32 * w + 16 * j + arow] = acc2[mt][j][r] + bd[j];
    }
    __syncthreads();

    // ---- phase 6: in-block segment reduce over sorted senders, atomic flush ----
    {
        const int c  = tid & 127;
        const int r0 = (tid >> 7) * 32;
        float sum = 0.f;
        int cur = s_send[r0];
        for (int e = r0; e < r0 + 32; ++e) {
            sum += s_msg[e][c];
            int nxt = (e + 1 < r0 + 32) ? s_send[e + 1] : -1;
            if (nxt != cur) {
                atomicAdd(&out[(size_t)cur * DO + c], sum);
                sum = 0.f;
                cur = nxt;
            }
        }
    }
}

__global__ __launch_bounds__(128) void div_count(
    const int* __restrict__ senders, float* __restrict__ out)
{
    int n = blockIdx.x, d = threadIdx.x;
    int lo = 0, hi = E_TOT;
    while (lo < hi) { int m = (lo + hi) >> 1; if (senders[m] < n) lo = m + 1; else hi = m; }
    int s0 = lo;
    hi = E_TOT;
    while (lo < hi) { int m = (lo + hi) >> 1; if (senders[m] < n + 1) lo = m + 1; else hi = m; }
    int cnt = lo - s0;
    if (cnt > 1) out[(size_t)n * DO + d] *= (1.0f / (float)cnt);
}

extern "C" void kernel_launch(void* const* d_in, const int* in_sizes, int n_in,
                              void* d_out, int out_size, void* d_ws, size_t ws_size,
                              hipStream_t stream)
{
    const float* n_embed   = (const float*)d_in[0];
    const float* e_embed   = (const float*)d_in[1];
    const int*   senders   = (const int*)d_in[2];
    const int*   receivers = (const int*)d_in[3];
    const float* W1        = (const float*)d_in[4];
    const float* b1        = (const float*)d_in[5];
    const float* W2        = (const float*)d_in[6];
    const float* b2        = (const float*)d_in[7];
    float* out = (float*)d_out;

    float* Ps = (float*)d_ws;                       // [NN][192]
    float* Pr = Ps + (size_t)NN * DH;               // [NN][192]

    pack_weights<<<(W1_FRAGS + W2_FRAGS + 255) / 256, 256, 0, stream>>>(W1, W2);
    zero_out<<<(NN * DO + 255) / 256, 256, 0, stream>>>(out);
    node_proj<<<dim3((NN + 63) / 64, 2), 256, 0, stream>>>(n_embed, b1, Ps);
    edge_mlp2<<<E_TOT / EB, 256, 0, stream>>>(
        e_embed, senders, receivers, Ps, Pr, b2, out);
    div_count<<<NN, 128, 0, stream>>>(senders, out);
}

// Round 4
// 100.390 us; speedup vs baseline: 9.5906x; 1.0732x over previous
//
#include <hip/hip_runtime.h>

#define E_TOT 320000
#define NN    10000
#define DN    128
#define DE    32
#define DH    192
#define DO    128
#define EB    64
#define SHS   208   // s_h row stride in ushorts (416 B, 16B-aligned)

typedef __attribute__((ext_vector_type(8))) short bf16x8;
typedef __attribute__((ext_vector_type(4))) float f32x4;

#define W1_FRAGS (9*12*64)
#define W2_FRAGS (6*8*64)
#define FRAGS_TOT (W1_FRAGS + W2_FRAGS)
__device__ __align__(16) unsigned short g_p1[W1_FRAGS * 8];
__device__ __align__(16) unsigned short g_p2[W2_FRAGS * 8];

__device__ __forceinline__ unsigned short f2bf(float f) {
    union { float f; unsigned u; } v; v.f = f;
    return (unsigned short)((v.u + 0x7FFFu + ((v.u >> 16) & 1u)) >> 16);
}
__device__ __forceinline__ float bflo(unsigned u) {
    union { unsigned v; float f; } t; t.v = u << 16; return t.f;
}
__device__ __forceinline__ float bfhi(unsigned u) {
    union { unsigned v; float f; } t; t.v = u & 0xFFFF0000u; return t.f;
}
__device__ __forceinline__ float tanh_fast(float x) {
    float ex = __expf(x + x);
    return 1.0f - 2.0f * __builtin_amdgcn_rcpf(ex + 1.0f);
}
__device__ __forceinline__ unsigned combine2(unsigned a, unsigned s, unsigned r) {
    float x0 = bflo(a) + bflo(s) + bflo(r);
    float x1 = bfhi(a) + bfhi(s) + bfhi(r);
    return (unsigned)f2bf(tanh_fast(x0)) | ((unsigned)f2bf(tanh_fast(x1)) << 16);
}

// ---------------------------------------------------------------------------
// prep: pack W1/W2 into fragment-major bf16 tables + zero the output
// ---------------------------------------------------------------------------
__global__ void prep(const float* __restrict__ W1, const float* __restrict__ W2,
                     float* __restrict__ outz)
{
    int f = blockIdx.x * 256 + threadIdx.x;
    unsigned short tmp[8];
    if (f < W1_FRAGS) {
        int kk = f / (12 * 64), nt = (f >> 6) % 12, lane = f & 63;
        int r0 = kk * 32 + ((lane >> 4) << 3);
        int c  = nt * 16 + (lane & 15);
        #pragma unroll
        for (int i = 0; i < 8; ++i) tmp[i] = f2bf(W1[(r0 + i) * DH + c]);
        *(uint4*)(g_p1 + (size_t)f * 8) = *(const uint4*)tmp;
    } else if (f < FRAGS_TOT) {
        int f2 = f - W1_FRAGS;
        int kk = f2 / (8 * 64), nt = (f2 >> 6) % 8, lane = f2 & 63;
        int r0 = kk * 32 + ((lane >> 4) << 3);
        int c  = nt * 16 + (lane & 15);
        #pragma unroll
        for (int i = 0; i < 8; ++i) tmp[i] = f2bf(W2[(r0 + i) * DO + c]);
        *(uint4*)(g_p2 + (size_t)f2 * 8) = *(const uint4*)tmp;
    } else {
        int z = f - FRAGS_TOT;
        if (z < NN * DO) outz[z] = 0.f;
    }
}

// ---------------------------------------------------------------------------
// node projections, bf16 output: P_s = n_embed@W1[0:128]+b1 (y=0), P_r = n_embed@W1[128:256] (y=1)
// ---------------------------------------------------------------------------
__global__ __launch_bounds__(256) void node_proj(
    const float* __restrict__ n_embed, const float* __restrict__ b1,
    unsigned short* __restrict__ P)
{
    __shared__ __align__(16) unsigned short s_a[64][136];
    const int tid  = threadIdx.x;
    const int half = blockIdx.y;
    const int n0   = blockIdx.x * 64;

    #pragma unroll
    for (int it = 0; it < 8; ++it) {
        int idx = tid + it * 256;
        int row = idx >> 5, c = idx & 31;
        float4 v = make_float4(0.f, 0.f, 0.f, 0.f);
        if (n0 + row < NN) v = ((const float4*)(n_embed + (size_t)(n0 + row) * DN))[c];
        unsigned short t[4] = { f2bf(v.x), f2bf(v.y), f2bf(v.z), f2bf(v.w) };
        *(uint2*)&s_a[row][c * 4] = *(const uint2*)t;
    }
    __syncthreads();

    const int lane = tid & 63, w = tid >> 6;
    const int arow = lane & 15, akb = (lane >> 4) * 8, rbase = (lane >> 4) * 4;

    f32x4 acc[4][3];
    #pragma unroll
    for (int mt = 0; mt < 4; ++mt)
        #pragma unroll
        for (int j = 0; j < 3; ++j) acc[mt][j] = (f32x4){0.f, 0.f, 0.f, 0.f};

    for (int kk = 0; kk < 4; ++kk) {
        bf16x8 a[4], b[3];
        #pragma unroll
        for (int mt = 0; mt < 4; ++mt)
            a[mt] = *(const bf16x8*)&s_a[mt * 16 + arow][kk * 32 + akb];
        #pragma unroll
        for (int j = 0; j < 3; ++j)
            b[j] = *(const bf16x8*)(g_p1 + (((size_t)(kk + 4 * half) * 12 + (3 * w + j)) * 64 + lane) * 8);
        #pragma unroll
        for (int mt = 0; mt < 4; ++mt)
            #pragma unroll
            for (int j = 0; j < 3; ++j)
                acc[mt][j] = __builtin_amdgcn_mfma_f32_16x16x32_bf16(a[mt], b[j], acc[mt][j], 0, 0, 0);
    }

    unsigned short* Pout = P + (size_t)half * NN * DH;
    float bj[3];
    #pragma unroll
    for (int j = 0; j < 3; ++j) bj[j] = (half == 0) ? b1[48 * w + 16 * j + arow] : 0.f;
    #pragma unroll
    for (int mt = 0; mt < 4; ++mt)
        #pragma unroll
        for (int j = 0; j < 3; ++j)
            #pragma unroll
            for (int r = 0; r < 4; ++r) {
                int row = n0 + mt * 16 + rbase + r;
                if (row < NN)
                    Pout[(size_t)row * DH + 48 * w + 16 * j + arow] = f2bf(acc[mt][j][r] + bj[j]);
            }
}

// ---------------------------------------------------------------------------
// fused edge kernel, early-issued wide P gather
// ---------------------------------------------------------------------------
__global__ __launch_bounds__(256, 3) void edge_mlp3(
    const float* __restrict__ e_embed,
    const int* __restrict__ senders, const int* __restrict__ receivers,
    const unsigned short* __restrict__ Ps, const unsigned short* __restrict__ Pr,
    const float* __restrict__ b2, float* __restrict__ out)
{
    __shared__ __align__(16) char s_buf[EB * 132 * 4];      // 33792 B
    __shared__ __align__(16) unsigned short s_e[EB][40];    // 5120 B
    __shared__ int s_send[EB];
    unsigned short (*s_h)[SHS] = (unsigned short(*)[SHS])s_buf;   // 26624 B used
    float          (*s_msg)[132] = (float(*)[132])s_buf;

    const int tid = threadIdx.x;
    const int nb8 = gridDim.x >> 3;                         // 625
    const int e0  = (((blockIdx.x & 7) * nb8) + (blockIdx.x >> 3)) * EB;  // XCD swizzle

    const int lane = tid & 63, w = tid >> 6;
    const int arow = lane & 15, akb = (lane >> 4) * 8, rbase = (lane >> 4) * 4;

    // ---- phase 0: EARLY wide P gather (edge ge, col-chunks 8*(q+4i)) ----
    const int ge = tid >> 2, q = tid & 3;
    const int sN = senders[e0 + ge], rN = receivers[e0 + ge];
    const unsigned short* psrow = Ps + (size_t)sN * DH;
    const unsigned short* prrow = Pr + (size_t)rN * DH;
    uint4 vs[6], vr[6];
    #pragma unroll
    for (int i = 0; i < 6; ++i) {
        vs[i] = *(const uint4*)(psrow + 8 * (q + 4 * i));
        vr[i] = *(const uint4*)(prrow + 8 * (q + 4 * i));
    }
    // GEMM1e B-fragments early too (L2-hot, block-uniform)
    bf16x8 b1f[3];
    #pragma unroll
    for (int j = 0; j < 3; ++j)
        b1f[j] = *(const bf16x8*)(g_p1 + (((size_t)8 * 12 + (3 * w + j)) * 64 + lane) * 8);

    if (tid < EB) s_send[tid] = senders[e0 + tid];
    #pragma unroll
    for (int it = 0; it < 2; ++it) {
        int idx = tid + it * 256;
        int row = idx >> 3, c = idx & 7;
        float4 v = ((const float4*)(e_embed + (size_t)(e0 + row) * DE))[c];
        unsigned short t[4] = { f2bf(v.x), f2bf(v.y), f2bf(v.z), f2bf(v.w) };
        *(uint2*)&s_e[row][c * 4] = *(const uint2*)t;
    }
    __syncthreads();

    // ---- phase 2: GEMM1e (K=32) with immediate bf16 spill to s_h (C-layout) ----
    #pragma unroll
    for (int mt = 0; mt < 4; ++mt) {
        bf16x8 a = *(const bf16x8*)&s_e[mt * 16 + arow][akb];
        #pragma unroll
        for (int j = 0; j < 3; ++j) {
            f32x4 z = (f32x4){0.f, 0.f, 0.f, 0.f};
            f32x4 acc = __builtin_amdgcn_mfma_f32_16x16x32_bf16(a, b1f[j], z, 0, 0, 0);
            #pragma unroll
            for (int r = 0; r < 4; ++r)
                s_h[mt * 16 + rbase + r][48 * w + 16 * j + arow] = f2bf(acc[r]);
        }
    }
    __syncthreads();

    // ---- phase 3: h = tanh(acc1 + Ps[s] + Pr[r]) in place, 16B chunks ----
    #pragma unroll
    for (int i = 0; i < 6; ++i) {
        unsigned short* hp = &s_h[ge][8 * (q + 4 * i)];
        uint4 av = *(uint4*)hp;
        uint4 res;
        res.x = combine2(av.x, vs[i].x, vr[i].x);
        res.y = combine2(av.y, vs[i].y, vr[i].y);
        res.z = combine2(av.z, vs[i].z, vr[i].z);
        res.w = combine2(av.w, vs[i].w, vr[i].w);
        *(uint4*)hp = res;
    }
    __syncthreads();

    // ---- phase 4: GEMM2  msg = h @ W2 ----
    f32x4 acc2[4][2];
    #pragma unroll
    for (int mt = 0; mt < 4; ++mt)
        #pragma unroll
        for (int j = 0; j < 2; ++j) acc2[mt][j] = (f32x4){0.f, 0.f, 0.f, 0.f};

    for (int kk = 0; kk < 6; ++kk) {
        bf16x8 a[4], b[2];
        #pragma unroll
        for (int mt = 0; mt < 4; ++mt)
            a[mt] = *(const bf16x8*)&s_h[mt * 16 + arow][kk * 32 + akb];
        #pragma unroll
        for (int j = 0; j < 2; ++j)
            b[j] = *(const bf16x8*)(g_p2 + (((size_t)kk * 8 + (2 * w + j)) * 64 + lane) * 8);
        #pragma unroll
        for (int mt = 0; mt < 4; ++mt)
            #pragma unroll
            for (int j = 0; j < 2; ++j)
                acc2[mt][j] = __builtin_amdgcn_mfma_f32_16x16x32_bf16(a[mt], b[j], acc2[mt][j], 0, 0, 0);
    }
    __syncthreads();   // s_h reads done (s_msg aliases)

    // ---- phase 5: msg (+bias) -> s_msg (fp32) ----
    {
        float bd[2];
        #pragma unroll
        for (int j = 0; j < 2; ++j) bd[j] = b2[32 * w + 16 * j + arow];
        #pragma unroll
        for (int mt = 0; mt < 4; ++mt)
            #pragma unroll
            for (int j = 0; j < 2; ++j)
                #pragma unroll
                for (int r = 0; r < 4; ++r)
                    s_msg[mt * 16 + rbase + r][32 * w + 16 * j + arow] = acc2[mt][j][r] + bd[j];
    }
    __syncthreads();

    // ---- phase 6: in-block segment reduce (sorted senders) -> atomics ----
    {
        const int c  = tid & 127;
        const int r0 = (tid >> 7) * 32;
        float sum = 0.f;
        int cur = s_send[r0];
        for (int e = r0; e < r0 + 32; ++e) {
            sum += s_msg[e][c];
            int nxt = (e + 1 < r0 + 32) ? s_send[e + 1] : -1;
            if (nxt != cur) {
                atomicAdd(&out[(size_t)cur * DO + c], sum);
                sum = 0.f;
                cur = nxt;
            }
        }
    }
}

__global__ __launch_bounds__(128) void div_count(
    const int* __restrict__ senders, float* __restrict__ out)
{
    int n = blockIdx.x, d = threadIdx.x;
    int lo = 0, hi = E_TOT;
    while (lo < hi) { int m = (lo + hi) >> 1; if (senders[m] < n) lo = m + 1; else hi = m; }
    int s0 = lo;
    hi = E_TOT;
    while (lo < hi) { int m = (lo + hi) >> 1; if (senders[m] < n + 1) lo = m + 1; else hi = m; }
    int cnt = lo - s0;
    if (cnt > 1) out[(size_t)n * DO + d] *= (1.0f / (float)cnt);
}

extern "C" void kernel_launch(void* const* d_in, const int* in_sizes, int n_in,
                              void* d_out, int out_size, void* d_ws, size_t ws_size,
                              hipStream_t stream)
{
    const float* n_embed   = (const float*)d_in[0];
    const float* e_embed   = (const float*)d_in[1];
    const int*   senders   = (const int*)d_in[2];
    const int*   receivers = (const int*)d_in[3];
    const float* W1        = (const float*)d_in[4];
    const float* b1        = (const float*)d_in[5];
    const float* W2        = (const float*)d_in[6];
    const float* b2        = (const float*)d_in[7];
    float* out = (float*)d_out;

    unsigned short* Ps = (unsigned short*)d_ws;        // [NN][192] bf16
    unsigned short* Pr = Ps + (size_t)NN * DH;         // [NN][192] bf16

    prep<<<(FRAGS_TOT + NN * DO + 255) / 256, 256, 0, stream>>>(W1, W2, out);
    node_proj<<<dim3((NN + 63) / 64, 2), 256, 0, stream>>>(n_embed, b1, Ps);
    edge_mlp3<<<E_TOT / EB, 256, 0, stream>>>(
        e_embed, senders, receivers, Ps, Pr, b2, out);
    div_count<<<NN, 128, 0, stream>>>(senders, out);
}